// Round 6
// baseline (487.166 us; speedup 1.0000x reference)
//
#include <hip/hip_runtime.h>
#include <hip/hip_bf16.h>

// HydraAttention  B=8 N=16384 C=256 NH=8 CH=32 H=W=128
// Token-major intermediates: q,k,v,mid = [b][n][C] bf16.
// K1 qkv_mfma: persistent token-tile (x in LDS once), j-loop x K-loop,
//     weights dbuf staged AFTER barrier (1-phase prefetch distance).
// K1b kv_reduce, K2 crpe<K>: unchanged from R5.
// K3 proj_mfma: same persistent structure, mid staged via gload16.

typedef __hip_bfloat16 bf16;
typedef __bf16 bf16x8 __attribute__((ext_vector_type(8)));
typedef unsigned short u16x8 __attribute__((ext_vector_type(8)));
typedef float f32x4 __attribute__((ext_vector_type(4)));
typedef float f32x8 __attribute__((ext_vector_type(8)));

#define SCALE_ 0.17677669529663687f

__device__ __forceinline__ unsigned short f2b(float f) {
  __hip_bfloat16 h = __float2bfloat16(f);
  return __builtin_bit_cast(unsigned short, h);
}
__device__ __forceinline__ float blo(unsigned u) {
  return __builtin_bit_cast(float, u << 16);
}
__device__ __forceinline__ float bhi(unsigned u) {
  return __builtin_bit_cast(float, u & 0xffff0000u);
}
__device__ __forceinline__ f32x8 unpack8(uint4 u) {
  f32x8 r;
  r[0] = blo(u.x); r[1] = bhi(u.x); r[2] = blo(u.y); r[3] = bhi(u.y);
  r[4] = blo(u.z); r[5] = bhi(u.z); r[6] = blo(u.w); r[7] = bhi(u.w);
  return r;
}
__device__ __forceinline__ uint4 pack8(float a0, float a1, float a2, float a3,
                                       float a4, float a5, float a6, float a7) {
  uint4 s;
  s.x = (unsigned)f2b(a0) | ((unsigned)f2b(a1) << 16);
  s.y = (unsigned)f2b(a2) | ((unsigned)f2b(a3) << 16);
  s.z = (unsigned)f2b(a4) | ((unsigned)f2b(a5) << 16);
  s.w = (unsigned)f2b(a6) | ((unsigned)f2b(a7) << 16);
  return s;
}
__device__ __forceinline__ void gload16(const void* g, void* l) {
  __builtin_amdgcn_global_load_lds(
      (const __attribute__((address_space(1))) unsigned int*)g,
      (__attribute__((address_space(3))) unsigned int*)l, 16, 0, 0);
}
__device__ __forceinline__ f32x4 mfma16(u16x8 a, u16x8 b, f32x4 c) {
  return __builtin_amdgcn_mfma_f32_16x16x32_bf16(
      __builtin_bit_cast(bf16x8, a), __builtin_bit_cast(bf16x8, b), c, 0, 0, 0);
}

// ------------------------------------------------------------- weight prep
__global__ __launch_bounds__(256) void prep_weights(
    const float* __restrict__ wqkv, const float* __restrict__ wproj,
    bf16* __restrict__ wqkvT, bf16* __restrict__ wprojT) {
  const int idx = blockIdx.x * 256 + threadIdx.x;
  if (idx < 768 * 256) {
    const int j = idx >> 8, k = idx & 255;
    wqkvT[idx] = __float2bfloat16(wqkv[k * 768 + j]);
  }
  if (idx < 256 * 256) {
    const int j = idx >> 8, k = idx & 255;
    wprojT[idx] = __float2bfloat16(wproj[k * 256 + j]);
  }
}

// --------------------------------------------------------------- K1: qkv MFMA
// grid (1024), block 256 (4 waves). Per block: 128 tokens, all 768 j.
// XL: x tile [128 tok][32 slot16] bf16, swizzle phys = s ^ (tok&7).
// WB: weight dbuf 2x8KB ([128 j][4 slot16], swz slot^((row>>1)&3));
//     reused as 16KB epilogue transpose scratch.
__global__ __launch_bounds__(256) void qkv_mfma(
    const float* __restrict__ x, const bf16* __restrict__ wT,
    bf16* __restrict__ qO, bf16* __restrict__ kO, bf16* __restrict__ vO) {
  __shared__ __align__(16) char XL[65536];
  __shared__ __align__(16) char WB[16384];
  const int tid = threadIdx.x;
  const int l = tid & 63, w = tid >> 6;
  const int wr = w >> 1, wc = w & 1;  // wr: j half, wc: token half
  const int t0 = (int)blockIdx.x << 7;
  const int b = t0 >> 14;
  const int n0 = t0 & 16383;

  // ---- x prologue: fp32 -> bf16, swizzled LDS, once per block
  {
    const int tk = tid >> 5;   // 0..7
    const int s = tid & 31;
    for (int r = 0; r < 16; ++r) {
      const int row = r * 8 + tk;
      const float4 a0 = *(const float4*)(x + (size_t)(t0 + row) * 256 + s * 8);
      const float4 a1 =
          *(const float4*)(x + (size_t)(t0 + row) * 256 + s * 8 + 4);
      u16x8 p;
      p[0] = f2b(a0.x); p[1] = f2b(a0.y); p[2] = f2b(a0.z); p[3] = f2b(a0.w);
      p[4] = f2b(a1.x); p[5] = f2b(a1.y); p[6] = f2b(a1.z); p[7] = f2b(a1.w);
      *(u16x8*)(XL + row * 512 + ((s ^ (row & 7)) << 4)) = p;
    }
  }

  // weight staging geometry (per wave)
  const int arow0 = w * 16 + (l >> 2), arow1 = arow0 + 64;
  const int asl = l & 3;
  const int aoff0 = ((asl ^ ((arow0 >> 1) & 3)) << 3);
  const int aoff1 = ((asl ^ ((arow1 >> 1) & 3)) << 3);
  const int ad0 = w * 1024, ad1 = 4096 + w * 1024;

  const int fr = l & 15;
  const int fq = l >> 4;
  const int fs = (fq ^ ((l >> 1) & 3)) << 4;  // A frag slot byte

  // B frag geometry: tokens + swizzle nibble per tt
  int btok[4], btsw[4];
#pragma unroll
  for (int tt = 0; tt < 4; ++tt) {
    btok[tt] = wc * 64 + tt * 16 + fr;
    btsw[tt] = btok[tt] & 7;
  }

#pragma unroll 1
  for (int jt = 0; jt < 6; ++jt) {
    const bf16* wbase = wT + (size_t)jt * 128 * 256;
    f32x4 acc[4][4];
#pragma unroll
    for (int m = 0; m < 4; ++m)
#pragma unroll
      for (int t = 0; t < 4; ++t) acc[m][t] = (f32x4){0.f, 0.f, 0.f, 0.f};

    // stage K-step 0 into buf0
    gload16(wbase + (size_t)arow0 * 256 + aoff0, WB + ad0);
    gload16(wbase + (size_t)arow1 * 256 + aoff1, WB + ad1);

#pragma unroll 1
    for (int t = 0; t < 8; ++t) {
      __syncthreads();  // drains stage(t) (issued one phase ago) + lds writes
      if (t < 7) {      // prefetch next K-step into the other buffer
        const int kn = (t + 1) * 32;
        const int nb = ((t + 1) & 1) << 13;
        gload16(wbase + (size_t)arow0 * 256 + kn + aoff0, WB + nb + ad0);
        gload16(wbase + (size_t)arow1 * 256 + kn + aoff1, WB + nb + ad1);
      }
      const char* Ac = WB + ((t & 1) << 13);
      u16x8 af[4], bfv[4];
#pragma unroll
      for (int m = 0; m < 4; ++m)
        af[m] = *(const u16x8*)(Ac + (wr * 64 + m * 16 + fr) * 64 + fs);
#pragma unroll
      for (int tt = 0; tt < 4; ++tt)
        bfv[tt] = *(const u16x8*)(XL + btok[tt] * 512 +
                                  (((4 * t + fq) ^ btsw[tt]) << 4));
#pragma unroll
      for (int m = 0; m < 4; ++m)
#pragma unroll
        for (int tt = 0; tt < 4; ++tt)
          acc[m][tt] = mfma16(af[m], bfv[tt], acc[m][tt]);
    }

    // ---- epilogue: transpose via WB (16KB), 2 rounds of 64 tokens
    const int region = jt >> 1;
    bf16* outp = (region == 0) ? qO : ((region == 1) ? kO : vO);
    const int jl = (jt & 1) * 128;
    __syncthreads();  // all frag reads of WB done
#pragma unroll 1
    for (int c = 0; c < 2; ++c) {
      if (wc == c) {
#pragma unroll
        for (int m = 0; m < 4; ++m) {
          const int jq = wr * 16 + m * 4 + fq;  // 8B quad in 128-j half
#pragma unroll
          for (int tt = 0; tt < 4; ++tt) {
            const int ltok = tt * 16 + fr;
            uint2 pk;
            pk.x = (unsigned)f2b(acc[m][tt][0]) |
                   ((unsigned)f2b(acc[m][tt][1]) << 16);
            pk.y = (unsigned)f2b(acc[m][tt][2]) |
                   ((unsigned)f2b(acc[m][tt][3]) << 16);
            *(uint2*)(WB + ltok * 256 + ((jq ^ (ltok & 15)) << 3)) = pk;
          }
        }
      }
      __syncthreads();
      const int seg = tid & 15;
#pragma unroll
      for (int r = 0; r < 4; ++r) {
        const int ltok = r * 16 + (tid >> 4);
        const int tsw = ltok & 15;
        const uint2 lo = *(const uint2*)(WB + ltok * 256 + (((2 * seg) ^ tsw) << 3));
        const uint2 hi =
            *(const uint2*)(WB + ltok * 256 + (((2 * seg + 1) ^ tsw) << 3));
        uint4 d;
        d.x = lo.x; d.y = lo.y; d.z = hi.x; d.w = hi.y;
        *(uint4*)&outp[((size_t)b * 16384 + n0 + c * 64 + ltok) * 256 + jl +
                       seg * 8] = d;
      }
      __syncthreads();
    }
  }
}

// ------------------------------------------------------------ K1b: kv reduce
__global__ __launch_bounds__(256) void kv_reduce(
    const bf16* __restrict__ kT, const bf16* __restrict__ vT,
    float* __restrict__ kv) {
  __shared__ float red[256 * 8];
  const int tid = threadIdx.x;
  const int b = blockIdx.y;
  const int seg = tid & 31;
  f32x8 part = (f32x8)0.f;

  for (int r = 0; r < 32; ++r) {
    const int token = blockIdx.x * 256 + r * 8 + (tid >> 5);
    const size_t roff = ((size_t)b * 16384 + token) * 256;
    const uint4 kd = *(const uint4*)(kT + roff + seg * 8);
    const f32x8 kf = unpack8(kd);
    float ss = 0.f;
#pragma unroll
    for (int i = 0; i < 8; ++i) ss += kf[i] * kf[i];
    ss += __shfl_xor(ss, 1);
    ss += __shfl_xor(ss, 2);
    const float inv = rsqrtf(ss);
    const uint4 vd = *(const uint4*)(vT + roff + seg * 8);
    const f32x8 vf = unpack8(vd);
#pragma unroll
    for (int i = 0; i < 8; ++i) part[i] += kf[i] * inv * vf[i];
  }
#pragma unroll
  for (int i = 0; i < 8; ++i) red[tid * 8 + i] = part[i];
  __syncthreads();
  if (tid < 32) {
    f32x8 s = (f32x8)0.f;
#pragma unroll
    for (int k = 0; k < 8; ++k)
#pragma unroll
      for (int i = 0; i < 8; ++i) s[i] += red[(tid + 32 * k) * 8 + i];
#pragma unroll
    for (int i = 0; i < 8; ++i)
      atomicAdd(&kv[b * 256 + seg * 8 + i], s[i]);
  }
}

// ------------------------------------------------- K2: crpe conv + combine
template <int K>
__global__ __launch_bounds__(256) void crpe_conv(
    const bf16* __restrict__ qT, const bf16* __restrict__ vT,
    const float* __restrict__ kvbuf, const float* __restrict__ wp,
    const float* __restrict__ bp, int OC, int hbase,
    bf16* __restrict__ mid) {
  constexpr int R = K / 2;
  constexpr int S = 16 + 2 * R;
  constexpr int NSLOT = 4 * ((S - 1) * 23 + 1);
  __shared__ __align__(16) char vs[NSLOT * 16];
  __shared__ float wlds[K * K * 32];
  __shared__ float blds[32];

  const int tid = threadIdx.x;
  const int hg = blockIdx.x;
  const int h = hbase + hg;
  const int tile = blockIdx.y;
  const int b = blockIdx.z;
  const int tx0 = (tile & 7) * 16, ty0 = (tile >> 3) * 16;
  const int px = tid & 15, py = tid >> 4;
  const int ocbase = hg * 32;

  for (int e = tid; e < S * S; e += 256) {
    const int ly = e / S, lx = e - ly * S;
    const int gy = ty0 - R + ly, gx = tx0 - R + lx;
    uint4 d0 = {0, 0, 0, 0}, d1 = {0, 0, 0, 0}, d2 = {0, 0, 0, 0},
          d3 = {0, 0, 0, 0};
    if (gy >= 0 && gy < 128 && gx >= 0 && gx < 128) {
      const uint4* src = (const uint4*)(vT +
          ((size_t)b * 16384 + gy * 128 + gx) * 256 + h * 32);
      d0 = src[0]; d1 = src[1]; d2 = src[2]; d3 = src[3];
    }
    const int p = ly * 22 + lx;
    const int sw = (p >> 1) & 3;
    char* base = vs + ((p << 2) << 4);
    *(uint4*)(base + ((0 ^ sw) << 4)) = d0;
    *(uint4*)(base + ((1 ^ sw) << 4)) = d1;
    *(uint4*)(base + ((2 ^ sw) << 4)) = d2;
    *(uint4*)(base + ((3 ^ sw) << 4)) = d3;
  }
  for (int e = tid; e < K * K * 32; e += 256)
    wlds[e] = wp[(e >> 5) * OC + ocbase + (e & 31)];
  if (tid < 32) blds[tid] = bp[ocbase + tid];
  __syncthreads();

  const float4* bl4 = (const float4*)blds;
  f32x8 acc[4];
#pragma unroll
  for (int cc = 0; cc < 4; ++cc) {
    const float4 b0 = bl4[cc * 2], b1 = bl4[cc * 2 + 1];
    acc[cc][0] = b0.x; acc[cc][1] = b0.y; acc[cc][2] = b0.z; acc[cc][3] = b0.w;
    acc[cc][4] = b1.x; acc[cc][5] = b1.y; acc[cc][6] = b1.z; acc[cc][7] = b1.w;
  }
  const float4* wlds4 = (const float4*)wlds;
#pragma unroll 1
  for (int ky = 0; ky < K; ++ky) {
#pragma unroll
    for (int kx = 0; kx < K; ++kx) {
      const int p = (py + ky) * 22 + (px + kx);
      const int tap = ky * K + kx;
      const int sw = (p >> 1) & 3;
      const char* base = vs + ((p << 2) << 4);
#pragma unroll
      for (int cc = 0; cc < 4; ++cc) {
        const uint4 vv = *(const uint4*)(base + ((cc ^ sw) << 4));
        const f32x8 vf = unpack8(vv);
        const float4 w0 = wlds4[tap * 8 + cc * 2];
        const float4 w1 = wlds4[tap * 8 + cc * 2 + 1];
        acc[cc][0] += vf[0] * w0.x; acc[cc][1] += vf[1] * w0.y;
        acc[cc][2] += vf[2] * w0.z; acc[cc][3] += vf[3] * w0.w;
        acc[cc][4] += vf[4] * w1.x; acc[cc][5] += vf[5] * w1.y;
        acc[cc][6] += vf[6] * w1.z; acc[cc][7] += vf[7] * w1.w;
      }
    }
  }

  const int n = (ty0 + py) * 128 + (tx0 + px);
  const size_t off = ((size_t)b * 16384 + n) * 256 + h * 32;
  const uint4* qsrc = (const uint4*)(qT + off);
  f32x8 qv[4];
  float ss = 0.f;
#pragma unroll
  for (int cc = 0; cc < 4; ++cc) {
    qv[cc] = unpack8(qsrc[cc]);
#pragma unroll
    for (int i = 0; i < 8; ++i) ss += qv[cc][i] * qv[cc][i];
  }
  const float qinv = rsqrtf(ss);
  const float4* kvp = (const float4*)(kvbuf + ((size_t)b * 8 + h) * 32);
  uint4* mdst = (uint4*)(mid + off);
#pragma unroll
  for (int cc = 0; cc < 4; ++cc) {
    const float4 ka = kvp[cc * 2], kb = kvp[cc * 2 + 1];
    float o[8];
    o[0] = SCALE_ * qv[cc][0] * qinv * ka.x + qv[cc][0] * acc[cc][0];
    o[1] = SCALE_ * qv[cc][1] * qinv * ka.y + qv[cc][1] * acc[cc][1];
    o[2] = SCALE_ * qv[cc][2] * qinv * ka.z + qv[cc][2] * acc[cc][2];
    o[3] = SCALE_ * qv[cc][3] * qinv * ka.w + qv[cc][3] * acc[cc][3];
    o[4] = SCALE_ * qv[cc][4] * qinv * kb.x + qv[cc][4] * acc[cc][4];
    o[5] = SCALE_ * qv[cc][5] * qinv * kb.y + qv[cc][5] * acc[cc][5];
    o[6] = SCALE_ * qv[cc][6] * qinv * kb.z + qv[cc][6] * acc[cc][6];
    o[7] = SCALE_ * qv[cc][7] * qinv * kb.w + qv[cc][7] * acc[cc][7];
    mdst[cc] = pack8(o[0], o[1], o[2], o[3], o[4], o[5], o[6], o[7]);
  }
}

// --------------------------------------------------------------- K3: proj MFMA
// grid (1024), block 256. Per block: 128 tokens, both 128-j tiles.
// XL: mid tile staged via gload16 (pre-swizzled source). WB: weight dbuf +
// fp32 epilogue scratch (4 rounds of 32 tokens).
__global__ __launch_bounds__(256) void proj_mfma(
    const bf16* __restrict__ mid, const bf16* __restrict__ wpT,
    const float* __restrict__ bproj, float* __restrict__ out) {
  __shared__ __align__(16) char XL[65536];
  __shared__ __align__(16) char WB[16384];
  const int tid = threadIdx.x;
  const int l = tid & 63, w = tid >> 6;
  const int wr = w >> 1, wc = w & 1;
  const int t0 = (int)blockIdx.x << 7;
  const int b = t0 >> 14;
  const int n0 = t0 & 16383;

  // ---- mid prologue: 16 gload16 shots per thread-wave (1KB each)
  {
    const int ltk = l >> 5;       // 0..1 within shot
    const int s = l & 31;
#pragma unroll 1
    for (int i = 0; i < 16; ++i) {
      const int shot_tok = w * 32 + i * 2;
      const int tok = shot_tok + ltk;
      gload16(mid + ((size_t)b * 16384 + n0 + tok) * 256 +
                  ((s ^ (tok & 7)) << 3),
              XL + shot_tok * 512);
    }
  }

  const int arow0 = w * 16 + (l >> 2), arow1 = arow0 + 64;
  const int asl = l & 3;
  const int aoff0 = ((asl ^ ((arow0 >> 1) & 3)) << 3);
  const int aoff1 = ((asl ^ ((arow1 >> 1) & 3)) << 3);
  const int ad0 = w * 1024, ad1 = 4096 + w * 1024;

  const int fr = l & 15;
  const int fq = l >> 4;
  const int fs = (fq ^ ((l >> 1) & 3)) << 4;

  int btok[4], btsw[4];
#pragma unroll
  for (int tt = 0; tt < 4; ++tt) {
    btok[tt] = wc * 64 + tt * 16 + fr;
    btsw[tt] = btok[tt] & 7;
  }

#pragma unroll 1
  for (int jt = 0; jt < 2; ++jt) {
    const bf16* wbase = wpT + (size_t)jt * 128 * 256;
    const int j0 = jt * 128;
    f32x4 acc[4][4];
#pragma unroll
    for (int m = 0; m < 4; ++m)
#pragma unroll
      for (int t = 0; t < 4; ++t) acc[m][t] = (f32x4){0.f, 0.f, 0.f, 0.f};

    gload16(wbase + (size_t)arow0 * 256 + aoff0, WB + ad0);
    gload16(wbase + (size_t)arow1 * 256 + aoff1, WB + ad1);

#pragma unroll 1
    for (int t = 0; t < 8; ++t) {
      __syncthreads();
      if (t < 7) {
        const int kn = (t + 1) * 32;
        const int nb = ((t + 1) & 1) << 13;
        gload16(wbase + (size_t)arow0 * 256 + kn + aoff0, WB + nb + ad0);
        gload16(wbase + (size_t)arow1 * 256 + kn + aoff1, WB + nb + ad1);
      }
      const char* Ac = WB + ((t & 1) << 13);
      u16x8 af[4], bfv[4];
#pragma unroll
      for (int m = 0; m < 4; ++m)
        af[m] = *(const u16x8*)(Ac + (wr * 64 + m * 16 + fr) * 64 + fs);
#pragma unroll
      for (int tt = 0; tt < 4; ++tt)
        bfv[tt] = *(const u16x8*)(XL + btok[tt] * 512 +
                                  (((4 * t + fq) ^ btsw[tt]) << 4));
#pragma unroll
      for (int m = 0; m < 4; ++m)
#pragma unroll
        for (int tt = 0; tt < 4; ++tt)
          acc[m][tt] = mfma16(af[m], bfv[tt], acc[m][tt]);
    }

    // bias
#pragma unroll
    for (int m = 0; m < 4; ++m) {
      const float4 bias =
          *(const float4*)&bproj[j0 + wr * 64 + m * 16 + fq * 4];
#pragma unroll
      for (int t = 0; t < 4; ++t) {
        acc[m][t][0] += bias.x;
        acc[m][t][1] += bias.y;
        acc[m][t][2] += bias.z;
        acc[m][t][3] += bias.w;
      }
    }

    // ---- epilogue: fp32 transpose via WB, 4 rounds of 32 tokens
    __syncthreads();
#pragma unroll 1
    for (int r = 0; r < 4; ++r) {
      if (wc == (r >> 1)) {
        const int tb = (r & 1) * 2;
#pragma unroll
        for (int m = 0; m < 4; ++m) {
          const int sq = wr * 16 + m * 4 + fq;  // 16B slot in 128-j half
#pragma unroll
          for (int ti = 0; ti < 2; ++ti) {
            const int tt = tb + ti;
            const int ltok = ti * 16 + fr;  // 0..31 within round
            float4 rv;
            rv.x = acc[m][tt][0]; rv.y = acc[m][tt][1];
            rv.z = acc[m][tt][2]; rv.w = acc[m][tt][3];
            *(float4*)(WB + ltok * 512 + ((sq ^ (ltok & 7)) << 4)) = rv;
          }
        }
      }
      __syncthreads();
#pragma unroll
      for (int i = 0; i < 2; ++i) {
        const int lin = i * 256 + tid;
        const int ltok = lin >> 5, seg = lin & 31;
        const float4 dv =
            *(const float4*)(WB + ltok * 512 + ((seg ^ (ltok & 7)) << 4));
        *(float4*)&out[(size_t)(t0 + r * 32 + ltok) * 256 + j0 + seg * 4] = dv;
        const int lin2 = lin + 512;
        const int ltok2 = lin2 >> 5, seg2 = lin2 & 31;
        const float4 dv2 =
            *(const float4*)(WB + ltok2 * 512 + ((seg2 ^ (ltok2 & 7)) << 4));
        *(float4*)&out[(size_t)(t0 + r * 32 + ltok2) * 256 + j0 + seg2 * 4] =
            dv2;
      }
      __syncthreads();
    }
  }
}

// ------------------------------------------------------------------- launcher
extern "C" void kernel_launch(void* const* d_in, const int* in_sizes, int n_in,
                              void* d_out, int out_size, void* d_ws,
                              size_t ws_size, hipStream_t stream) {
  const float* x     = (const float*)d_in[0];
  const float* wqkv  = (const float*)d_in[1];
  const float* wproj = (const float*)d_in[2];
  const float* bproj = (const float*)d_in[3];
  const float* w3 = (const float*)d_in[4];
  const float* b3 = (const float*)d_in[5];
  const float* w5 = (const float*)d_in[6];
  const float* b5 = (const float*)d_in[7];
  const float* w7 = (const float*)d_in[8];
  const float* b7 = (const float*)d_in[9];
  float* out = (float*)d_out;

  const size_t PLANE = (size_t)8 * 16384 * 256;
  bf16* qT  = (bf16*)d_ws;
  bf16* vT  = qT + PLANE;
  bf16* kT  = vT + PLANE;
  bf16* mid = kT;                     // alias: k dead after kv_reduce
  float* kv = (float*)(kT + PLANE);
  bf16* wqkvT  = (bf16*)(kv + 2048);
  bf16* wprojT = wqkvT + 768 * 256;

  hipMemsetAsync(kv, 0, 2048 * sizeof(float), stream);
  prep_weights<<<dim3(768), 256, 0, stream>>>(wqkv, wproj, wqkvT, wprojT);
  qkv_mfma<<<dim3(1024), 256, 0, stream>>>(x, wqkvT, qT, kT, vT);
  kv_reduce<<<dim3(64, 8), 256, 0, stream>>>(kT, vT, kv);
  crpe_conv<3><<<dim3(2, 64, 8), 256, 0, stream>>>(qT, vT, kv, w3, b3, 64, 0, mid);
  crpe_conv<5><<<dim3(3, 64, 8), 256, 0, stream>>>(qT, vT, kv, w5, b5, 96, 2, mid);
  crpe_conv<7><<<dim3(3, 64, 8), 256, 0, stream>>>(qT, vT, kv, w7, b7, 96, 5, mid);
  proj_mfma<<<dim3(1024), 256, 0, stream>>>(mid, wprojT, bproj, out);
}

// Round 7
// 373.514 us; speedup vs baseline: 1.3043x; 1.3043x over previous
//
#include <hip/hip_runtime.h>
#include <hip/hip_bf16.h>

// HydraAttention  B=8 N=16384 C=256 NH=8 CH=32 H=W=128
// R7 = R5 structure + counted-vmcnt barriers (T3/T4), 3-deep x-reg pipeline
// (qkv), 3-deep LDS pipeline (proj), setprio (T5), fused crpe launch.

typedef __hip_bfloat16 bf16;
typedef __bf16 bf16x8 __attribute__((ext_vector_type(8)));
typedef unsigned short u16x8 __attribute__((ext_vector_type(8)));
typedef float f32x4 __attribute__((ext_vector_type(4)));
typedef float f32x8 __attribute__((ext_vector_type(8)));

#define SCALE_ 0.17677669529663687f

__device__ __forceinline__ unsigned short f2b(float f) {
  __hip_bfloat16 h = __float2bfloat16(f);
  return __builtin_bit_cast(unsigned short, h);
}
__device__ __forceinline__ float blo(unsigned u) {
  return __builtin_bit_cast(float, u << 16);
}
__device__ __forceinline__ float bhi(unsigned u) {
  return __builtin_bit_cast(float, u & 0xffff0000u);
}
__device__ __forceinline__ f32x8 unpack8(uint4 u) {
  f32x8 r;
  r[0] = blo(u.x); r[1] = bhi(u.x); r[2] = blo(u.y); r[3] = bhi(u.y);
  r[4] = blo(u.z); r[5] = bhi(u.z); r[6] = blo(u.w); r[7] = bhi(u.w);
  return r;
}
__device__ __forceinline__ uint4 pack8(float a0, float a1, float a2, float a3,
                                       float a4, float a5, float a6, float a7) {
  uint4 s;
  s.x = (unsigned)f2b(a0) | ((unsigned)f2b(a1) << 16);
  s.y = (unsigned)f2b(a2) | ((unsigned)f2b(a3) << 16);
  s.z = (unsigned)f2b(a4) | ((unsigned)f2b(a5) << 16);
  s.w = (unsigned)f2b(a6) | ((unsigned)f2b(a7) << 16);
  return s;
}
__device__ __forceinline__ void gload16(const void* g, void* l) {
  __builtin_amdgcn_global_load_lds(
      (const __attribute__((address_space(1))) unsigned int*)g,
      (__attribute__((address_space(3))) unsigned int*)l, 16, 0, 0);
}
__device__ __forceinline__ f32x4 mfma16(u16x8 a, u16x8 b, f32x4 c) {
  return __builtin_amdgcn_mfma_f32_16x16x32_bf16(
      __builtin_bit_cast(bf16x8, a), __builtin_bit_cast(bf16x8, b), c, 0, 0, 0);
}
// counted-vmcnt barrier: leave N VMEM ops in flight across the barrier
__device__ __forceinline__ void barrier_vm4() {
  asm volatile("s_waitcnt vmcnt(4) lgkmcnt(0)" ::: "memory");
  __builtin_amdgcn_s_barrier();
  asm volatile("" ::: "memory");
}
__device__ __forceinline__ void barrier_vm0() {
  asm volatile("s_waitcnt vmcnt(0) lgkmcnt(0)" ::: "memory");
  __builtin_amdgcn_s_barrier();
  asm volatile("" ::: "memory");
}
__device__ __forceinline__ void barrier_vm8() {
  asm volatile("s_waitcnt vmcnt(8) lgkmcnt(0)" ::: "memory");
  __builtin_amdgcn_s_barrier();
  asm volatile("" ::: "memory");
}

// ------------------------------------------------------------- weight prep
__global__ __launch_bounds__(256) void prep_weights(
    const float* __restrict__ wqkv, const float* __restrict__ wproj,
    bf16* __restrict__ wqkvT, bf16* __restrict__ wprojT) {
  const int idx = blockIdx.x * 256 + threadIdx.x;
  if (idx < 768 * 256) {
    const int j = idx >> 8, k = idx & 255;
    wqkvT[idx] = __float2bfloat16(wqkv[k * 768 + j]);
  }
  if (idx < 256 * 256) {
    const int j = idx >> 8, k = idx & 255;
    wprojT[idx] = __float2bfloat16(wproj[k * 256 + j]);
  }
}

// --------------------------------------------------------------- K1: qkv MFMA
// grid (6, 1024), block 256 (4 waves). M=j(128), N=tokens(128), BK=32.
// Weights: gload16 dbuf (1-phase distance, L2-hot). x: 3-deep reg rotation
// (2-phase distance), counted vmcnt(4) keeps x-loads alive across barriers.
__global__ __launch_bounds__(256) void qkv_mfma(
    const float* __restrict__ x, const bf16* __restrict__ wT,
    bf16* __restrict__ qO, bf16* __restrict__ kO, bf16* __restrict__ vO) {
  __shared__ __align__(16) char LDSU[32768];
  char* As = LDSU;           // weights dbuf 2x8KB
  char* Bs = LDSU + 16384;   // x dbuf 2x8KB
  const int tid = threadIdx.x;
  const int l = tid & 63, w = tid >> 6;
  const int wr = w >> 1, wc = w & 1;  // wr: j half, wc: token half

  const int lin = blockIdx.y * 6 + blockIdx.x;
  const int xcd = lin & 7, qq = lin >> 3;
  const int jt = qq % 6;
  const int ttile = xcd * 128 + qq / 6;
  const int j0 = jt << 7;
  const int t0 = ttile << 7;

  f32x4 acc[4][4];
#pragma unroll
  for (int m = 0; m < 4; ++m)
#pragma unroll
    for (int t = 0; t < 4; ++t) acc[m][t] = (f32x4){0.f, 0.f, 0.f, 0.f};

  const int arow0 = w * 16 + (l >> 2), arow1 = arow0 + 64;
  const int asl = l & 3;
  const bf16* asrc0 =
      wT + (size_t)(j0 + arow0) * 256 + ((asl ^ ((arow0 >> 1) & 3)) << 3);
  const bf16* asrc1 =
      wT + (size_t)(j0 + arow1) * 256 + ((asl ^ ((arow1 >> 1) & 3)) << 3);
  const int ad0 = w * 1024, ad1 = 4096 + w * 1024;

  const int brow = tid >> 1, bkh = tid & 1;
  const float* xp = x + (size_t)(t0 + brow) * 256 + bkh * 16;
  const int bsw = (brow >> 1) & 3;
  const int bw0 = brow * 64 + (((bkh << 1) ^ bsw) << 4);
  const int bw1 = brow * 64 + ((((bkh << 1) | 1) ^ bsw) << 4);

  const int fr = l & 15;
  const int fq = l >> 4;
  const int fs = (fq ^ ((l >> 1) & 3)) << 4;

  float4 xs[3][4];  // 3-deep k-step rotation; all indices literal after unroll

  // ---- prologue: w0 gloads first, then x k=0..2; ds_write k0 -> buf0
  gload16(asrc0, As + ad0);
  gload16(asrc1, As + ad1);
#pragma unroll
  for (int s = 0; s < 3; ++s)
#pragma unroll
    for (int i = 0; i < 4; ++i)
      xs[s][i] = *(const float4*)(xp + s * 32 + i * 4);
  {
    u16x8 p0, p1;
    p0[0] = f2b(xs[0][0].x); p0[1] = f2b(xs[0][0].y);
    p0[2] = f2b(xs[0][0].z); p0[3] = f2b(xs[0][0].w);
    p0[4] = f2b(xs[0][1].x); p0[5] = f2b(xs[0][1].y);
    p0[6] = f2b(xs[0][1].z); p0[7] = f2b(xs[0][1].w);
    p1[0] = f2b(xs[0][2].x); p1[1] = f2b(xs[0][2].y);
    p1[2] = f2b(xs[0][2].z); p1[3] = f2b(xs[0][2].w);
    p1[4] = f2b(xs[0][3].x); p1[5] = f2b(xs[0][3].y);
    p1[6] = f2b(xs[0][3].z); p1[7] = f2b(xs[0][3].w);
    *(u16x8*)(Bs + bw0) = p0;
    *(u16x8*)(Bs + bw1) = p1;
  }
  barrier_vm8();  // w0 retired (older than x0); x1,x2 stay in flight

#pragma unroll
  for (int t = 0; t < 8; ++t) {
    // issue next weight tile (1-phase distance)
    if (t < 7) {
      const int kn = (t + 1) << 5;
      char* Adst = As + (((t + 1) & 1) << 13);
      gload16(asrc0 + kn, Adst + ad0);
      gload16(asrc1 + kn, Adst + ad1);
    }
    // issue x loads for k-step t+3 (2-phase distance)
    if (t < 5) {
#pragma unroll
      for (int i = 0; i < 4; ++i)
        xs[t % 3][i] = *(const float4*)(xp + (t + 3) * 32 + i * 4);
    }
    // fragments + MFMA on current buffers
    const char* Ac = As + ((t & 1) << 13);
    const char* Bc = Bs + ((t & 1) << 13);
    u16x8 af[4], bfv[4];
#pragma unroll
    for (int m = 0; m < 4; ++m)
      af[m] = *(const u16x8*)(Ac + (wr * 64 + m * 16 + fr) * 64 + fs);
#pragma unroll
    for (int tt = 0; tt < 4; ++tt)
      bfv[tt] = *(const u16x8*)(Bc + (wc * 64 + tt * 16 + fr) * 64 + fs);
    __builtin_amdgcn_s_setprio(1);
#pragma unroll
    for (int m = 0; m < 4; ++m)
#pragma unroll
      for (int tt = 0; tt < 4; ++tt)
        acc[m][tt] = mfma16(af[m], bfv[tt], acc[m][tt]);
    __builtin_amdgcn_s_setprio(0);
    // convert + LDS-write next x tile (data loaded 2 phases ago)
    if (t < 7) {
      const float4* xv = xs[(t + 1) % 3];
      u16x8 p0, p1;
      p0[0] = f2b(xv[0].x); p0[1] = f2b(xv[0].y);
      p0[2] = f2b(xv[0].z); p0[3] = f2b(xv[0].w);
      p0[4] = f2b(xv[1].x); p0[5] = f2b(xv[1].y);
      p0[6] = f2b(xv[1].z); p0[7] = f2b(xv[1].w);
      p1[0] = f2b(xv[2].x); p1[1] = f2b(xv[2].y);
      p1[2] = f2b(xv[2].z); p1[3] = f2b(xv[2].w);
      p1[4] = f2b(xv[3].x); p1[5] = f2b(xv[3].y);
      p1[6] = f2b(xv[3].z); p1[7] = f2b(xv[3].w);
      char* Bdst = Bs + (((t + 1) & 1) << 13);
      *(u16x8*)(Bdst + bw0) = p0;
      *(u16x8*)(Bdst + bw1) = p1;
    }
    if (t < 5) barrier_vm4();        // w(t+1) retired; x(t+3) stays in flight
    else if (t < 7) barrier_vm0();   // tail: drain
  }
  __syncthreads();

  // ---- epilogue (R5): transpose through LDS, coalesced 256B-run stores
#pragma unroll
  for (int m = 0; m < 4; ++m) {
    const int jq = wr * 16 + m * 4 + fq;
#pragma unroll
    for (int t = 0; t < 4; ++t) {
      const int token = wc * 64 + t * 16 + fr;
      const int p = jq ^ (token & 15);
      uint2 pk;
      pk.x = (unsigned)f2b(acc[m][t][0]) | ((unsigned)f2b(acc[m][t][1]) << 16);
      pk.y = (unsigned)f2b(acc[m][t][2]) | ((unsigned)f2b(acc[m][t][3]) << 16);
      *(uint2*)(LDSU + token * 256 + (p << 3)) = pk;
    }
  }
  __syncthreads();

  const int region = j0 >> 8;  // 0:q 1:k 2:v
  bf16* outp = (region == 0) ? qO : ((region == 1) ? kO : vO);
  const int b = t0 >> 14;
  const int n0 = t0 & 16383;
  const int jl = j0 & 255;
  const int seg = tid & 15;
#pragma unroll
  for (int r = 0; r < 8; ++r) {
    const int token = r * 16 + (tid >> 4);
    const int tsw = token & 15;
    const uint2 lo = *(const uint2*)(LDSU + token * 256 + (((2 * seg) ^ tsw) << 3));
    const uint2 hi =
        *(const uint2*)(LDSU + token * 256 + (((2 * seg + 1) ^ tsw) << 3));
    uint4 d;
    d.x = lo.x; d.y = lo.y; d.z = hi.x; d.w = hi.y;
    *(uint4*)&outp[((size_t)b * 16384 + n0 + token) * 256 + jl + seg * 8] = d;
  }
}

// ------------------------------------------------------------ K1b: kv reduce
__global__ __launch_bounds__(256) void kv_reduce(
    const bf16* __restrict__ kT, const bf16* __restrict__ vT,
    float* __restrict__ kv) {
  __shared__ float red[256 * 8];
  const int tid = threadIdx.x;
  const int b = blockIdx.y;
  const int seg = tid & 31;
  f32x8 part = (f32x8)0.f;

  for (int r = 0; r < 32; ++r) {
    const int token = blockIdx.x * 256 + r * 8 + (tid >> 5);
    const size_t roff = ((size_t)b * 16384 + token) * 256;
    const uint4 kd = *(const uint4*)(kT + roff + seg * 8);
    const f32x8 kf = unpack8(kd);
    float ss = 0.f;
#pragma unroll
    for (int i = 0; i < 8; ++i) ss += kf[i] * kf[i];
    ss += __shfl_xor(ss, 1);
    ss += __shfl_xor(ss, 2);
    const float inv = rsqrtf(ss);
    const uint4 vd = *(const uint4*)(vT + roff + seg * 8);
    const f32x8 vf = unpack8(vd);
#pragma unroll
    for (int i = 0; i < 8; ++i) part[i] += kf[i] * inv * vf[i];
  }
#pragma unroll
  for (int i = 0; i < 8; ++i) red[tid * 8 + i] = part[i];
  __syncthreads();
  if (tid < 32) {
    f32x8 s = (f32x8)0.f;
#pragma unroll
    for (int k = 0; k < 8; ++k)
#pragma unroll
      for (int i = 0; i < 8; ++i) s[i] += red[(tid + 32 * k) * 8 + i];
#pragma unroll
    for (int i = 0; i < 8; ++i)
      atomicAdd(&kv[b * 256 + seg * 8 + i], s[i]);
  }
}

// ------------------------------------------------- K2: crpe conv + combine
// Fused single launch: grid (8, 64, 8), h = blockIdx.x. Carved smem (37.5KB).
#define CRPE_SMEM 37632

template <int K>
__device__ __forceinline__ void crpe_impl(
    char* smem, const bf16* __restrict__ qT, const bf16* __restrict__ vT,
    const float* __restrict__ kvbuf, const float* __restrict__ wp,
    const float* __restrict__ bp, int OC, int hg, int h,
    bf16* __restrict__ mid) {
  constexpr int R = K / 2;
  constexpr int S = 16 + 2 * R;
  constexpr int NSLOT = 4 * ((S - 1) * 23 + 1);
  char* vs = smem;
  float* wlds = (float*)(smem + NSLOT * 16);
  float* blds = wlds + K * K * 32;

  const int tid = threadIdx.x;
  const int tile = blockIdx.y;
  const int b = blockIdx.z;
  const int tx0 = (tile & 7) * 16, ty0 = (tile >> 3) * 16;
  const int px = tid & 15, py = tid >> 4;
  const int ocbase = hg * 32;

  for (int e = tid; e < S * S; e += 256) {
    const int ly = e / S, lx = e - ly * S;
    const int gy = ty0 - R + ly, gx = tx0 - R + lx;
    uint4 d0 = {0, 0, 0, 0}, d1 = {0, 0, 0, 0}, d2 = {0, 0, 0, 0},
          d3 = {0, 0, 0, 0};
    if (gy >= 0 && gy < 128 && gx >= 0 && gx < 128) {
      const uint4* src = (const uint4*)(vT +
          ((size_t)b * 16384 + gy * 128 + gx) * 256 + h * 32);
      d0 = src[0]; d1 = src[1]; d2 = src[2]; d3 = src[3];
    }
    const int p = ly * 22 + lx;
    const int sw = (p >> 1) & 3;
    char* base = vs + ((p << 2) << 4);
    *(uint4*)(base + ((0 ^ sw) << 4)) = d0;
    *(uint4*)(base + ((1 ^ sw) << 4)) = d1;
    *(uint4*)(base + ((2 ^ sw) << 4)) = d2;
    *(uint4*)(base + ((3 ^ sw) << 4)) = d3;
  }
  for (int e = tid; e < K * K * 32; e += 256)
    wlds[e] = wp[(e >> 5) * OC + ocbase + (e & 31)];
  if (tid < 32) blds[tid] = bp[ocbase + tid];
  __syncthreads();

  const float4* bl4 = (const float4*)blds;
  f32x8 acc[4];
#pragma unroll
  for (int cc = 0; cc < 4; ++cc) {
    const float4 b0 = bl4[cc * 2], b1 = bl4[cc * 2 + 1];
    acc[cc][0] = b0.x; acc[cc][1] = b0.y; acc[cc][2] = b0.z; acc[cc][3] = b0.w;
    acc[cc][4] = b1.x; acc[cc][5] = b1.y; acc[cc][6] = b1.z; acc[cc][7] = b1.w;
  }
  const float4* wlds4 = (const float4*)wlds;
#pragma unroll 1
  for (int ky = 0; ky < K; ++ky) {
#pragma unroll
    for (int kx = 0; kx < K; ++kx) {
      const int p = (py + ky) * 22 + (px + kx);
      const int tap = ky * K + kx;
      const int sw = (p >> 1) & 3;
      const char* base = vs + ((p << 2) << 4);
#pragma unroll
      for (int cc = 0; cc < 4; ++cc) {
        const uint4 vv = *(const uint4*)(base + ((cc ^ sw) << 4));
        const f32x8 vf = unpack8(vv);
        const float4 w0 = wlds4[tap * 8 + cc * 2];
        const float4 w1 = wlds4[tap * 8 + cc * 2 + 1];
        acc[cc][0] += vf[0] * w0.x; acc[cc][1] += vf[1] * w0.y;
        acc[cc][2] += vf[2] * w0.z; acc[cc][3] += vf[3] * w0.w;
        acc[cc][4] += vf[4] * w1.x; acc[cc][5] += vf[5] * w1.y;
        acc[cc][6] += vf[6] * w1.z; acc[cc][7] += vf[7] * w1.w;
      }
    }
  }

  const int n = (ty0 + py) * 128 + (tx0 + px);
  const size_t off = ((size_t)b * 16384 + n) * 256 + h * 32;
  const uint4* qsrc = (const uint4*)(qT + off);
  f32x8 qv[4];
  float ss = 0.f;
#pragma unroll
  for (int cc = 0; cc < 4; ++cc) {
    qv[cc] = unpack8(qsrc[cc]);
#pragma unroll
    for (int i = 0; i < 8; ++i) ss += qv[cc][i] * qv[cc][i];
  }
  const float qinv = rsqrtf(ss);
  const float4* kvp = (const float4*)(kvbuf + ((size_t)b * 8 + h) * 32);
  uint4* mdst = (uint4*)(mid + off);
#pragma unroll
  for (int cc = 0; cc < 4; ++cc) {
    const float4 ka = kvp[cc * 2], kb = kvp[cc * 2 + 1];
    float o[8];
    o[0] = SCALE_ * qv[cc][0] * qinv * ka.x + qv[cc][0] * acc[cc][0];
    o[1] = SCALE_ * qv[cc][1] * qinv * ka.y + qv[cc][1] * acc[cc][1];
    o[2] = SCALE_ * qv[cc][2] * qinv * ka.z + qv[cc][2] * acc[cc][2];
    o[3] = SCALE_ * qv[cc][3] * qinv * ka.w + qv[cc][3] * acc[cc][3];
    o[4] = SCALE_ * qv[cc][4] * qinv * kb.x + qv[cc][4] * acc[cc][4];
    o[5] = SCALE_ * qv[cc][5] * qinv * kb.y + qv[cc][5] * acc[cc][5];
    o[6] = SCALE_ * qv[cc][6] * qinv * kb.z + qv[cc][6] * acc[cc][6];
    o[7] = SCALE_ * qv[cc][7] * qinv * kb.w + qv[cc][7] * acc[cc][7];
    mdst[cc] = pack8(o[0], o[1], o[2], o[3], o[4], o[5], o[6], o[7]);
  }
}

__global__ __launch_bounds__(256) void crpe_all(
    const bf16* __restrict__ qT, const bf16* __restrict__ vT,
    const float* __restrict__ kvbuf,
    const float* __restrict__ w3, const float* __restrict__ b3,
    const float* __restrict__ w5, const float* __restrict__ b5,
    const float* __restrict__ w7, const float* __restrict__ b7,
    bf16* __restrict__ mid) {
  __shared__ __align__(16) char smem[CRPE_SMEM];
  const int h = blockIdx.x;
  if (h < 2)
    crpe_impl<3>(smem, qT, vT, kvbuf, w3, b3, 64, h, h, mid);
  else if (h < 5)
    crpe_impl<5>(smem, qT, vT, kvbuf, w5, b5, 96, h - 2, h, mid);
  else
    crpe_impl<7>(smem, qT, vT, kvbuf, w7, b7, 96, h - 5, h, mid);
}

// --------------------------------------------------------------- K3: proj MFMA
// grid (2, 1024), block 256. 3-deep LDS pipeline (2-phase gload distance),
// counted vmcnt(4) barriers, setprio. R5 epilogue.
__global__ __launch_bounds__(256) void proj_mfma(
    const bf16* __restrict__ mid, const bf16* __restrict__ wpT,
    const float* __restrict__ bproj, float* __restrict__ out) {
  __shared__ __align__(16) char LDSU[49152];
  char* As = LDSU;            // 3 x 8KB
  char* Bs = LDSU + 24576;    // 3 x 8KB
  const int tid = threadIdx.x;
  const int l = tid & 63, w = tid >> 6;
  const int wr = w >> 1, wc = w & 1;

  const int lin = blockIdx.y * 2 + blockIdx.x;
  const int xcd = lin & 7, qq = lin >> 3;
  const int jt = qq & 1;
  const int ttile = xcd * 128 + (qq >> 1);
  const int j0 = jt << 7;
  const int tk0 = ttile << 7;

  f32x4 acc[4][4];
#pragma unroll
  for (int m = 0; m < 4; ++m)
#pragma unroll
    for (int t = 0; t < 4; ++t) acc[m][t] = (f32x4){0.f, 0.f, 0.f, 0.f};

  const int row0 = w * 16 + (l >> 2), row1 = row0 + 64;
  const int sl = l & 3;
  const int sw0 = (row0 >> 1) & 3, sw1 = (row1 >> 1) & 3;
  const bf16* asrc0 = wpT + (size_t)(j0 + row0) * 256 + ((sl ^ sw0) << 3);
  const bf16* asrc1 = wpT + (size_t)(j0 + row1) * 256 + ((sl ^ sw1) << 3);
  const bf16* bsrc0 = mid + (size_t)(tk0 + row0) * 256 + ((sl ^ sw0) << 3);
  const bf16* bsrc1 = mid + (size_t)(tk0 + row1) * 256 + ((sl ^ sw1) << 3);
  const int d0 = w * 1024, d1 = 4096 + w * 1024;

  const int fr = l & 15;
  const int fq = l >> 4;
  const int fs = (fq ^ ((l >> 1) & 3)) << 4;

  // prologue: k0 -> buf0, k1 -> buf1
  gload16(asrc0, As + d0);
  gload16(asrc1, As + d1);
  gload16(bsrc0, Bs + d0);
  gload16(bsrc1, Bs + d1);
  gload16(asrc0 + 32, As + 8192 + d0);
  gload16(asrc1 + 32, As + 8192 + d1);
  gload16(bsrc0 + 32, Bs + 8192 + d0);
  gload16(bsrc1 + 32, Bs + 8192 + d1);
  barrier_vm4();  // k0 retired; k1 stays in flight

#pragma unroll
  for (int t = 0; t < 8; ++t) {
    if (t < 6) {  // issue k-step t+2 (2-phase distance)
      const int kn = (t + 2) << 5;
      const int nb = ((t + 2) % 3) * 8192;
      gload16(asrc0 + kn, As + nb + d0);
      gload16(asrc1 + kn, As + nb + d1);
      gload16(bsrc0 + kn, Bs + nb + d0);
      gload16(bsrc1 + kn, Bs + nb + d1);
    }
    const char* Ac = As + (t % 3) * 8192;
    const char* Bc = Bs + (t % 3) * 8192;
    u16x8 af[4], bfv[4];
#pragma unroll
    for (int m = 0; m < 4; ++m)
      af[m] = *(const u16x8*)(Ac + (wr * 64 + m * 16 + fr) * 64 + fs);
#pragma unroll
    for (int tt = 0; tt < 4; ++tt)
      bfv[tt] = *(const u16x8*)(Bc + (wc * 64 + tt * 16 + fr) * 64 + fs);
    __builtin_amdgcn_s_setprio(1);
#pragma unroll
    for (int m = 0; m < 4; ++m)
#pragma unroll
      for (int tt = 0; tt < 4; ++tt)
        acc[m][tt] = mfma16(af[m], bfv[tt], acc[m][tt]);
    __builtin_amdgcn_s_setprio(0);
    if (t < 6) barrier_vm4();       // k(t+1) retired; k(t+2) in flight
    else if (t < 7) barrier_vm0();  // tail
  }
  __syncthreads();

  // bias
#pragma unroll
  for (int m = 0; m < 4; ++m) {
    const float4 bias = *(const float4*)&bproj[j0 + wr * 64 + m * 16 + fq * 4];
#pragma unroll
    for (int t = 0; t < 4; ++t) {
      acc[m][t][0] += bias.x;
      acc[m][t][1] += bias.y;
      acc[m][t][2] += bias.z;
      acc[m][t][3] += bias.w;
    }
  }

  // epilogue (R5): fp32 transpose via LDS, 2 chunks of 64 tokens
  for (int chunk = 0; chunk < 2; ++chunk) {
    if (wc == chunk) {
#pragma unroll
      for (int m = 0; m < 4; ++m) {
        const int jq = wr * 16 + m * 4 + fq;
#pragma unroll
        for (int t = 0; t < 4; ++t) {
          const int ltok = t * 16 + fr;
          const int p = jq ^ (ltok & 15);
          float4 r;
          r.x = acc[m][t][0]; r.y = acc[m][t][1];
          r.z = acc[m][t][2]; r.w = acc[m][t][3];
          *(float4*)(LDSU + ltok * 512 + (p << 4)) = r;
        }
      }
    }
    __syncthreads();
    const int seg = tid & 31;
#pragma unroll
    for (int r = 0; r < 8; ++r) {
      const int ltok = r * 8 + (tid >> 5);
      const int p = seg ^ (ltok & 15);
      const float4 dv = *(const float4*)(LDSU + ltok * 512 + (p << 4));
      *(float4*)&out[(size_t)(tk0 + chunk * 64 + ltok) * 256 + j0 + seg * 4] = dv;
    }
    __syncthreads();
  }
}

// ------------------------------------------------------------------- launcher
extern "C" void kernel_launch(void* const* d_in, const int* in_sizes, int n_in,
                              void* d_out, int out_size, void* d_ws,
                              size_t ws_size, hipStream_t stream) {
  const float* x     = (const float*)d_in[0];
  const float* wqkv  = (const float*)d_in[1];
  const float* wproj = (const float*)d_in[2];
  const float* bproj = (const float*)d_in[3];
  const float* w3 = (const float*)d_in[4];
  const float* b3 = (const float*)d_in[5];
  const float* w5 = (const float*)d_in[6];
  const float* b5 = (const float*)d_in[7];
  const float* w7 = (const float*)d_in[8];
  const float* b7 = (const float*)d_in[9];
  float* out = (float*)d_out;

  const size_t PLANE = (size_t)8 * 16384 * 256;
  bf16* qT  = (bf16*)d_ws;
  bf16* vT  = qT + PLANE;
  bf16* kT  = vT + PLANE;
  bf16* mid = kT;                     // alias: k dead after kv_reduce
  float* kv = (float*)(kT + PLANE);
  bf16* wqkvT  = (bf16*)(kv + 2048);
  bf16* wprojT = wqkvT + 768 * 256;

  hipMemsetAsync(kv, 0, 2048 * sizeof(float), stream);
  prep_weights<<<dim3(768), 256, 0, stream>>>(wqkv, wproj, wqkvT, wprojT);
  qkv_mfma<<<dim3(6, 1024), 256, 0, stream>>>(x, wqkvT, qT, kT, vT);
  kv_reduce<<<dim3(64, 8), 256, 0, stream>>>(kT, vT, kv);
  crpe_all<<<dim3(8, 64, 8), 256, 0, stream>>>(qT, vT, kv, w3, b3, w5, b5, w7,
                                               b7, mid);
  proj_mfma<<<dim3(2, 1024), 256, 0, stream>>>(mid, wprojT, bproj, out);
}